// Round 2
// baseline (1199.759 us; speedup 1.0000x reference)
//
#include <hip/hip_runtime.h>

typedef unsigned short u16;
typedef unsigned int u32;
typedef __attribute__((ext_vector_type(8))) short bf16x8;
typedef __attribute__((ext_vector_type(4))) float f32x4;

#define N_NODES 50000
#define N_EDGES 800000

__device__ __forceinline__ float bf2f(u16 u) {
    union { u32 i; float f; } v; v.i = ((u32)u) << 16; return v.f;
}
__device__ __forceinline__ u16 f2bf(float f) {
    union { u32 i; float f; } v; v.f = f;
    u32 i = v.i;
    return (u16)((i + 0x7FFFu + ((i >> 16) & 1u)) >> 16);
}
// dtype-agnostic load: fl!=0 -> float32 buffer, else bf16 (u16) buffer
__device__ __forceinline__ float ldf(const void* p, int i, int fl) {
    return fl ? ((const float*)p)[i] : bf2f(((const u16*)p)[i]);
}
__device__ __forceinline__ int getflag(const int* flag) {
    return __builtin_amdgcn_readfirstlane(*flag);
}

// ---------------- dtype detection ----------------
// x ~ N(0,1). bf16 halfwords never decode to |v|>=2^16; float32 low-mantissa
// halfwords are ~uniform 16-bit -> ~44% decode to exponent >= 143.
__global__ void k_detect(const u16* __restrict__ xr, int* __restrict__ flag) {
    __shared__ int sc[256];
    int t = threadIdx.x;
    int c = 0;
    for (int i = t; i < 4096; i += 256) {
        u32 e = (xr[i] >> 7) & 0xFF;
        if (e >= 143) c++;
    }
    sc[t] = c;
    __syncthreads();
    for (int s = 128; s > 0; s >>= 1) {
        if (t < s) sc[t] += sc[t + s];
        __syncthreads();
    }
    if (t == 0) *flag = (sc[0] > 64) ? 1 : 0;   // 1 = float32, 0 = bf16
}

__global__ void k_canon_ea(const void* __restrict__ ea, float* __restrict__ eaf,
                           const int* __restrict__ flag) {
    int fl = getflag(flag);
    int e = blockIdx.x * 256 + threadIdx.x;
    if (e < N_EDGES) eaf[e] = ldf(ea, e, fl);
}

// ---------------- weight prep ----------------
__global__ void k_transpose128(const void* __restrict__ src, u16* __restrict__ dst,
                               const int* __restrict__ flag) {
    int fl = getflag(flag);
    int id = blockIdx.x * 256 + threadIdx.x;   // 16384 total
    if (id < 128 * 128) {
        int k = id >> 7, n = id & 127;
        dst[n * 128 + k] = f2bf(ldf(src, id, fl));
    }
}

__global__ void k_bcat(const void* __restrict__ bq, const void* __restrict__ bk,
                       const void* __restrict__ bv, const void* __restrict__ bs,
                       float* __restrict__ out, const int* __restrict__ flag) {
    int fl = getflag(flag);
    int t = threadIdx.x;  // 512
    const void* p = (t < 128) ? bq : (t < 256) ? bk : (t < 384) ? bv : bs;
    out[t] = ldf(p, t & 127, fl);
}

// ---------------- embed: node-side lin1  y = x @ W1[:64] + b1 ----------------
__global__ __launch_bounds__(256) void k_embed_lin1(
    const void* __restrict__ x, const void* __restrict__ w1,
    const void* __restrict__ b1, float* __restrict__ y,
    const int* __restrict__ flag)
{
    __shared__ float sx[2][64];
    int fl = getflag(flag);
    int t = threadIdx.x;
    int col = t & 127, half = t >> 7;
    float wreg[64];
    #pragma unroll
    for (int k = 0; k < 64; k++) wreg[k] = ldf(w1, k * 128 + col, fl);
    float bias = ldf(b1, col, fl);
    int base = blockIdx.x * 64;
    for (int it = 0; it < 32; ++it) {
        __syncthreads();
        if (t < 128) {
            int nh = base + it * 2 + (t >> 6);
            sx[t >> 6][t & 63] = (nh < N_NODES) ? ldf(x, nh * 64 + (t & 63), fl) : 0.f;
        }
        __syncthreads();
        float acc = bias;
        #pragma unroll
        for (int k = 0; k < 64; k++) acc = fmaf(sx[half][k], wreg[k], acc);
        int n = base + it * 2 + half;
        if (n < N_NODES) y[(size_t)n * 128 + col] = acc;
    }
}

// ---------------- CSR build ----------------
__global__ void k_degree(const int* __restrict__ dst, int* __restrict__ cnt) {
    int e = blockIdx.x * 256 + threadIdx.x;
    if (e < N_EDGES) atomicAdd(&cnt[dst[e]], 1);
}

__global__ __launch_bounds__(1024) void k_scan(const int* __restrict__ cnt,
                                               int* __restrict__ row_start,
                                               int* __restrict__ nxt)
{
    __shared__ int wsum[16];
    __shared__ int s_tot;
    int t = threadIdx.x, lane = t & 63, wid = t >> 6;
    int run = 0;
    for (int base = 0; base < N_NODES; base += 8192) {
        int i0 = base + t * 8;
        int v[8], pre[8];
        int s = 0;
        #pragma unroll
        for (int j = 0; j < 8; j++) {
            int i = i0 + j;
            v[j] = (i < N_NODES) ? cnt[i] : 0;
            pre[j] = s;
            s += v[j];
        }
        int tsum = s;
        int sc = tsum;
        #pragma unroll
        for (int off = 1; off < 64; off <<= 1) {
            int o = __shfl_up(sc, off);
            if (lane >= off) sc += o;
        }
        if (lane == 63) wsum[wid] = sc;
        __syncthreads();
        if (t == 0) {
            int acc2 = 0;
            #pragma unroll
            for (int k2 = 0; k2 < 16; k2++) { int vv = wsum[k2]; wsum[k2] = acc2; acc2 += vv; }
            s_tot = acc2;
        }
        __syncthreads();
        int texcl = run + wsum[wid] + (sc - tsum);
        #pragma unroll
        for (int j = 0; j < 8; j++) {
            int i = i0 + j;
            if (i < N_NODES) { int ex = texcl + pre[j]; row_start[i] = ex; nxt[i] = ex; }
        }
        run += s_tot;
        __syncthreads();
    }
    if (t == 0) row_start[N_NODES] = run;
}

__global__ void k_scatter(const int* __restrict__ dst, int* __restrict__ nxt,
                          int* __restrict__ eids) {
    int e = blockIdx.x * 256 + threadIdx.x;
    if (e < N_EDGES) { int p = atomicAdd(&nxt[dst[e]], 1); eids[p] = e; }
}

// ---------------- embed: per-edge MLP + atomic aggregate ----------------
// wave = 16-edge MFMA M-tile; A layout: m=lane&15, k=(lane>>4)*8+j (+32*kb)
// C layout: col=lane&15, row=(lane>>4)*4+reg
__global__ __launch_bounds__(256) void k_embed_edges(
    const float* __restrict__ y,
    const int* __restrict__ srcp, const int* __restrict__ dstp,
    const float* __restrict__ eaf,
    const void* __restrict__ w1, const void* __restrict__ lng, const void* __restrict__ lnb,
    const u16* __restrict__ w2t, const void* __restrict__ b2,
    float* __restrict__ h1, const int* __restrict__ flag)
{
    __shared__ u16 sB[128 * 136];   // W2^T, padded rows (2-way bank conflict = free)
    int fl = getflag(flag);
    int t = threadIdx.x;
    for (int c = t; c < 128 * 32; c += 256) {
        int row = c >> 5, ch = c & 31;
        *(ushort4*)&sB[row * 136 + ch * 4] = *(const ushort4*)&w2t[row * 128 + ch * 4];
    }
    int l = t & 63, w = t >> 6;
    int m = l & 15, q = l >> 4;

    float w1e[4][8], g1c[4][8], b1c[4][8];
    #pragma unroll
    for (int kb = 0; kb < 4; kb++)
        #pragma unroll
        for (int j = 0; j < 8; j++) {
            int f = kb * 32 + q * 8 + j;
            w1e[kb][j] = ldf(w1, 64 * 128 + f, fl);
            g1c[kb][j] = ldf(lng, f, fl);
            b1c[kb][j] = ldf(lnb, f, fl);
        }
    float b2c[8], g2c[8], b2n[8];
    #pragma unroll
    for (int nb = 0; nb < 8; nb++) {
        int c = nb * 16 + m;
        b2c[nb] = ldf(b2, c, fl);
        g2c[nb] = ldf(lng, c, fl);
        b2n[nb] = ldf(lnb, c, fl);
    }
    __syncthreads();

    f32x4 zf = {0.f, 0.f, 0.f, 0.f};
    for (int bt = blockIdx.x; bt < N_EDGES / 64; bt += gridDim.x) {
        int e = bt * 64 + w * 16 + m;
        int srcn = srcp[e];
        int dstn = dstp[e];
        float av = eaf[e];

        // lin1 (edge part) + relu + LN stats
        float a[4][8];
        float s1 = 0.f, s2 = 0.f;
        const float* yrow = y + (size_t)srcn * 128 + q * 8;
        #pragma unroll
        for (int kb = 0; kb < 4; kb++) {
            const float4* p = (const float4*)(yrow + kb * 32);
            float4 u0 = p[0], u1 = p[1];
            float tv[8] = {u0.x, u0.y, u0.z, u0.w, u1.x, u1.y, u1.z, u1.w};
            #pragma unroll
            for (int j = 0; j < 8; j++) {
                float vv = fmaxf(fmaf(av, w1e[kb][j], tv[j]), 0.f);
                a[kb][j] = vv;
                s1 += vv; s2 = fmaf(vv, vv, s2);
            }
        }
        s1 += __shfl_xor(s1, 16); s2 += __shfl_xor(s2, 16);
        s1 += __shfl_xor(s1, 32); s2 += __shfl_xor(s2, 32);
        float mu = s1 * (1.f / 128.f);
        float rs = rsqrtf(s2 * (1.f / 128.f) - mu * mu + 1e-5f);

        bf16x8 afrag[4];
        #pragma unroll
        for (int kb = 0; kb < 4; kb++)
            #pragma unroll
            for (int j = 0; j < 8; j++)
                afrag[kb][j] = (short)f2bf(fmaf((a[kb][j] - mu) * rs, g1c[kb][j], b1c[kb][j]));

        f32x4 acc[8];
        #pragma unroll
        for (int nb = 0; nb < 8; nb++) acc[nb] = zf;
        #pragma unroll
        for (int nb = 0; nb < 8; nb++) {
            const u16* brow = &sB[(nb * 16 + m) * 136 + q * 8];
            #pragma unroll
            for (int kb = 0; kb < 4; kb++) {
                bf16x8 bfrag = *(const bf16x8*)(brow + kb * 32);
                acc[nb] = __builtin_amdgcn_mfma_f32_16x16x32_bf16(afrag[kb], bfrag, acc[nb], 0, 0, 0);
            }
        }
        // bias + relu + LN + atomic scatter
        #pragma unroll
        for (int r = 0; r < 4; r++) {
            float z[8]; float t1 = 0.f, t2 = 0.f;
            #pragma unroll
            for (int nb = 0; nb < 8; nb++) {
                float vv = fmaxf(acc[nb][r] + b2c[nb], 0.f);
                z[nb] = vv; t1 += vv; t2 = fmaf(vv, vv, t2);
            }
            #pragma unroll
            for (int o = 1; o < 16; o <<= 1) { t1 += __shfl_xor(t1, o); t2 += __shfl_xor(t2, o); }
            float mu2 = t1 * (1.f / 128.f);
            float rs2 = rsqrtf(t2 * (1.f / 128.f) - mu2 * mu2 + 1e-5f);
            int dr = __shfl(dstn, q * 4 + r);
            float* hrow = h1 + (size_t)dr * 128 + m;
            #pragma unroll
            for (int nb = 0; nb < 8; nb++) {
                float ov = fmaf((z[nb] - mu2) * rs2, g2c[nb], b2n[nb]);
                unsafeAtomicAdd(hrow + nb * 16, ov);
            }
        }
    }
}

// ---------------- fused q/k/v/skip projection GEMM ----------------
__global__ __launch_bounds__(256) void k_proj(
    const float* __restrict__ hin, const u16* __restrict__ wt,
    const float* __restrict__ bcat, u16* __restrict__ outp)
{
    __shared__ u16 sA[64 * 136];
    __shared__ u16 sB[128 * 136];
    int t = threadIdx.x;
    int l = t & 63, w = t >> 6;
    int m = l & 15, q = l >> 4;
    int rowbase = blockIdx.x * 64;
    for (int c = t; c < 64 * 32; c += 256) {
        int row = c >> 5, ch = c & 31;
        int gr = rowbase + row;
        float4 v;
        if (gr < N_NODES) v = *(const float4*)&hin[(size_t)gr * 128 + ch * 4];
        else v = make_float4(0.f, 0.f, 0.f, 0.f);
        ushort4 pk;
        pk.x = f2bf(v.x); pk.y = f2bf(v.y); pk.z = f2bf(v.z); pk.w = f2bf(v.w);
        *(ushort4*)&sA[row * 136 + ch * 4] = pk;
    }
    __syncthreads();
    bf16x8 afrag[4];
    #pragma unroll
    for (int kb = 0; kb < 4; kb++)
        afrag[kb] = *(const bf16x8*)&sA[(w * 16 + m) * 136 + kb * 32 + q * 8];

    f32x4 zf = {0.f, 0.f, 0.f, 0.f};
    for (int g = 0; g < 4; ++g) {
        __syncthreads();
        for (int c = t; c < 128 * 32; c += 256) {
            int row = c >> 5, ch = c & 31;
            *(ushort4*)&sB[row * 136 + ch * 4] = *(const ushort4*)&wt[(g * 128 + row) * 128 + ch * 4];
        }
        __syncthreads();
        f32x4 acc[8];
        #pragma unroll
        for (int nb = 0; nb < 8; nb++) acc[nb] = zf;
        #pragma unroll
        for (int nb = 0; nb < 8; nb++) {
            const u16* brow = &sB[(nb * 16 + m) * 136 + q * 8];
            #pragma unroll
            for (int kb = 0; kb < 4; kb++) {
                bf16x8 bfrag = *(const bf16x8*)(brow + kb * 32);
                acc[nb] = __builtin_amdgcn_mfma_f32_16x16x32_bf16(afrag[kb], bfrag, acc[nb], 0, 0, 0);
            }
        }
        #pragma unroll
        for (int nb = 0; nb < 8; nb++) {
            int col = g * 128 + nb * 16 + m;
            float bb = bcat[col];
            #pragma unroll
            for (int r = 0; r < 4; r++) {
                int row = rowbase + w * 16 + q * 4 + r;
                if (row < N_NODES) outp[(size_t)row * 512 + col] = f2bf(acc[nb][r] + bb);
            }
        }
    }
}

// ---------------- attention: wave per dst node, online softmax over in-edges ----------------
__global__ __launch_bounds__(256) void k_attn(
    const u16* __restrict__ qkvs,
    const int* __restrict__ rowst, const int* __restrict__ eids,
    const int* __restrict__ srcp, const float* __restrict__ eaf,
    const void* __restrict__ wep, float* __restrict__ hout,
    const int* __restrict__ flag)
{
    int fl = getflag(flag);
    int t = threadIdx.x;
    int l = t & 63, w = t >> 6;
    int dstn = blockIdx.x * 4 + w;        // grid*4 == N exactly
    int f0 = l * 2;                       // features 2l, 2l+1; head = l>>4
    u32 qu = *(const u32*)&qkvs[(size_t)dstn * 512 + f0];
    const float scale = 0.17677669529663687f;  // 1/sqrt(32)
    float q0 = bf2f((u16)(qu & 0xffff)) * scale;
    float q1 = bf2f((u16)(qu >> 16)) * scale;
    float we0 = ldf(wep, f0, fl);
    float we1 = ldf(wep, f0 + 1, fl);
    float mi = -INFINITY, si = 0.f, a0 = 0.f, a1 = 0.f;
    int rs = rowst[dstn], re = rowst[dstn + 1];
    for (int i = rs; i < re; ++i) {
        int eid = eids[i];
        int sn = srcp[eid];
        float av = eaf[eid];
        const u16* srow = &qkvs[(size_t)sn * 512 + f0];
        u32 ku = *(const u32*)(srow + 128);
        float k0 = fmaf(av, we0, bf2f((u16)(ku & 0xffff)));
        float k1 = fmaf(av, we1, bf2f((u16)(ku >> 16)));
        float p = fmaf(q0, k0, q1 * k1);
        p += __shfl_xor(p, 1); p += __shfl_xor(p, 2);
        p += __shfl_xor(p, 4); p += __shfl_xor(p, 8);
        float mn = fmaxf(mi, p);
        float fs = __expf(mi - mn);       // exp(-inf)=0 on first edge
        float pe = __expf(p - mn);
        u32 vu = *(const u32*)(srow + 256);
        float v0 = fmaf(av, we0, bf2f((u16)(vu & 0xffff)));
        float v1 = fmaf(av, we1, bf2f((u16)(vu >> 16)));
        si = fmaf(si, fs, pe);
        a0 = fmaf(a0, fs, pe * v0);
        a1 = fmaf(a1, fs, pe * v1);
        mi = mn;
    }
    float inv = 1.f / (si + 1e-16f);
    u32 su = *(const u32*)&qkvs[(size_t)dstn * 512 + 384 + f0];
    float o0 = fmaxf(fmaf(a0, inv, bf2f((u16)(su & 0xffff))), 0.f);
    float o1 = fmaxf(fmaf(a1, inv, bf2f((u16)(su >> 16))), 0.f);
    float2 o; o.x = o0; o.y = o1;
    *(float2*)&hout[(size_t)dstn * 128 + f0] = o;
}

// ---------------- global mean pool ----------------
__global__ __launch_bounds__(256) void k_pool(
    const float* __restrict__ h, const int* __restrict__ batch,
    float* __restrict__ gsum, float* __restrict__ gcnt)
{
    __shared__ float ssum[8 * 128];
    __shared__ float scnt[8];
    int t = threadIdx.x;
    for (int i = t; i < 8 * 128; i += 256) ssum[i] = 0.f;
    if (t < 8) scnt[t] = 0.f;
    __syncthreads();
    int f = t & 127, half = t >> 7;
    int per = (N_NODES + gridDim.x - 1) / gridDim.x;
    int lo = blockIdx.x * per;
    int hi = lo + per; if (hi > N_NODES) hi = N_NODES;
    float racc = 0.f; float rcnt = 0.f; int rg = -1;
    for (int n = lo + half; n < hi; n += 2) {
        int g = batch[n];
        if (g != rg) {
            if (rg >= 0) { atomicAdd(&ssum[rg * 128 + f], racc); if (f == 0) atomicAdd(&scnt[rg], rcnt); }
            rg = g; racc = 0.f; rcnt = 0.f;
        }
        racc += h[(size_t)n * 128 + f];
        rcnt += 1.f;
    }
    if (rg >= 0) { atomicAdd(&ssum[rg * 128 + f], racc); if (f == 0) atomicAdd(&scnt[rg], rcnt); }
    __syncthreads();
    for (int i = t; i < 8 * 128; i += 256) unsafeAtomicAdd(&gsum[i], ssum[i]);
    if (t < 8) unsafeAtomicAdd(&gcnt[t], scnt[t]);
}

__global__ void k_out(const float* __restrict__ gsum, const float* __restrict__ gcnt,
                      void* __restrict__ outp, const int* __restrict__ flag) {
    int fl = getflag(flag);
    int t = threadIdx.x;  // 1024
    float c = fmaxf(gcnt[t >> 7], 1.f);
    float v = gsum[t] / c;
    if (fl) ((float*)outp)[t] = v;
    else ((u16*)outp)[t] = f2bf(v);
}

extern "C" void kernel_launch(void* const* d_in, const int* in_sizes, int n_in,
                              void* d_out, int out_size, void* d_ws, size_t ws_size,
                              hipStream_t stream)
{
    (void)in_sizes; (void)n_in; (void)out_size; (void)ws_size;
    const void* x    = d_in[0];
    const int* ei    = (const int*)d_in[1];
    const void* ea   = d_in[2];
    const int* batch = (const int*)d_in[3];
    const void* w1   = d_in[4];
    const void* b1   = d_in[5];
    const void* lng  = d_in[6];
    const void* lnb  = d_in[7];
    const void* b2   = d_in[9];
    const int* srcp = ei;
    const int* dstp = ei + N_EDGES;

    char* wsb = (char*)d_ws;
    size_t cur = 0;
    auto alloc = [&](size_t sz) -> void* {
        void* p = wsb + cur;
        cur += (sz + 255) & ~(size_t)255;
        return p;
    };
    float* y      = (float*)alloc((size_t)N_NODES * 128 * 4);   // reused as h3
    float* h1     = (float*)alloc((size_t)N_NODES * 128 * 4);
    float* h2     = (float*)alloc((size_t)N_NODES * 128 * 4);
    u16*   qkvs   = (u16*)  alloc((size_t)N_NODES * 512 * 2);
    float* eaf    = (float*)alloc((size_t)N_EDGES * 4);
    u16*   w2t    = (u16*)  alloc(128 * 128 * 2);
    u16*   wcat1  = (u16*)  alloc(512 * 128 * 2);
    u16*   wcat2  = (u16*)  alloc(512 * 128 * 2);
    float* bcat1  = (float*)alloc(512 * 4);
    float* bcat2  = (float*)alloc(512 * 4);
    int*   cntdeg = (int*)  alloc((size_t)N_NODES * 4);
    int*   rowst  = (int*)  alloc((size_t)(N_NODES + 1) * 4);
    int*   nxt    = (int*)  alloc((size_t)N_NODES * 4);
    int*   eids   = (int*)  alloc((size_t)N_EDGES * 4);
    float* gsum   = (float*)alloc((8 * 128 + 8) * 4);
    int*   dtflag = (int*)  alloc(256);
    float* h3 = y;

    hipMemsetAsync(h1, 0, (size_t)N_NODES * 128 * 4, stream);
    hipMemsetAsync(cntdeg, 0, (size_t)N_NODES * 4, stream);
    hipMemsetAsync(gsum, 0, (8 * 128 + 8) * 4, stream);

    k_detect<<<1, 256, 0, stream>>>((const u16*)x, dtflag);
    k_canon_ea<<<3125, 256, 0, stream>>>(ea, eaf, dtflag);

    k_transpose128<<<64, 256, 0, stream>>>(d_in[8], w2t, dtflag);
    const int wi1[4] = {10, 12, 14, 17}, wi2[4] = {19, 21, 23, 26};
    for (int j = 0; j < 4; j++)
        k_transpose128<<<64, 256, 0, stream>>>(d_in[wi1[j]], wcat1 + j * 16384, dtflag);
    for (int j = 0; j < 4; j++)
        k_transpose128<<<64, 256, 0, stream>>>(d_in[wi2[j]], wcat2 + j * 16384, dtflag);
    k_bcat<<<1, 512, 0, stream>>>(d_in[11], d_in[13], d_in[15], d_in[18], bcat1, dtflag);
    k_bcat<<<1, 512, 0, stream>>>(d_in[20], d_in[22], d_in[24], d_in[27], bcat2, dtflag);

    k_embed_lin1<<<782, 256, 0, stream>>>(x, w1, b1, y, dtflag);
    k_degree<<<3125, 256, 0, stream>>>(dstp, cntdeg);
    k_scan<<<1, 1024, 0, stream>>>(cntdeg, rowst, nxt);
    k_scatter<<<3125, 256, 0, stream>>>(dstp, nxt, eids);
    k_embed_edges<<<1024, 256, 0, stream>>>(y, srcp, dstp, eaf, w1, lng, lnb, w2t, b2, h1, dtflag);
    k_proj<<<782, 256, 0, stream>>>(h1, wcat1, bcat1, qkvs);
    k_attn<<<12500, 256, 0, stream>>>(qkvs, rowst, eids, srcp, eaf, d_in[16], h2, dtflag);
    k_proj<<<782, 256, 0, stream>>>(h2, wcat2, bcat2, qkvs);
    k_attn<<<12500, 256, 0, stream>>>(qkvs, rowst, eids, srcp, eaf, d_in[25], h3, dtflag);
    k_pool<<<128, 256, 0, stream>>>(h3, batch, gsum, gsum + 8 * 128);
    k_out<<<1, 1024, 0, stream>>>(gsum, gsum + 8 * 128, d_out, dtflag);
}